// Round 7
// baseline (166.734 us; speedup 1.0000x reference)
//
#include <hip/hip_runtime.h>
#include <math.h>

#define Bn   64
#define Nn   512
#define Dn   256
#define IMGn 51

typedef __attribute__((ext_vector_type(8))) short bf16x8;
typedef __attribute__((ext_vector_type(4))) float f32x4;
typedef __attribute__((ext_vector_type(4))) unsigned short u16x4;

__device__ inline unsigned short f2b(float f) {            // fp32 -> bf16 RNE
    union { float f; unsigned u; } v; v.f = f;
    unsigned r = v.u + 0x7fffu + ((v.u >> 16) & 1u);
    return (unsigned short)(r >> 16);
}

// ---- fused prep: l2norm(input_2)->T, cvt(input_1)->A0, cvt weights ------------
__global__ __launch_bounds__(256) void k_prep(const float* __restrict__ in1,
                                              const float* __restrict__ in2,
                                              const float* __restrict__ w0,
                                              const float* __restrict__ w1,
                                              const float* __restrict__ wf,
                                              unsigned short* __restrict__ A0,
                                              unsigned short* __restrict__ T,
                                              unsigned short* __restrict__ w0b,
                                              unsigned short* __restrict__ w1b,
                                              unsigned short* __restrict__ wfb) {
    const int bid = blockIdx.x, tid = threadIdx.x;
    if (bid < 8192) {                                      // norm: 4 rows/block
        const int row = bid * 4 + (tid >> 6);
        const int lane = tid & 63;
        float4 v = ((const float4*)(in2 + (size_t)row * Dn))[lane];
        float ss = v.x * v.x + v.y * v.y + v.z * v.z + v.w * v.w;
#pragma unroll
        for (int m = 1; m < 64; m <<= 1) ss += __shfl_xor(ss, m);
        float inv = 1.0f / fmaxf(sqrtf(ss), 1e-8f);
        u16x4 o = { f2b(v.x*inv), f2b(v.y*inv), f2b(v.z*inv), f2b(v.w*inv) };
        ((u16x4*)(T + (size_t)row * Dn))[lane] = o;
    } else if (bid < 10240) {                              // cvt input_1
        int i = (bid - 8192) * 256 + tid;
#pragma unroll
        for (int q = 0; q < 4; ++q, i += 524288) {
            float4 v = ((const float4*)in1)[i];
            u16x4 o = { f2b(v.x), f2b(v.y), f2b(v.z), f2b(v.w) };
            ((u16x4*)A0)[i] = o;
        }
    } else {                                               // cvt weights
        const int b2 = bid - 10240;
        const float* src = (b2 < 64) ? w0 : (b2 < 128) ? w1 : wf;
        unsigned short* dst = (b2 < 64) ? w0b : (b2 < 128) ? w1b : wfb;
        const int i = (b2 & 63) * 256 + tid;
        float4 v = ((const float4*)src)[i];
        u16x4 o = { f2b(v.x), f2b(v.y), f2b(v.z), f2b(v.w) };
        ((u16x4*)dst)[i] = o;
    }
}

// ---- staging / fragment helpers (shared) --------------------------------------
__device__ inline void stage128x32(const unsigned short* __restrict__ src, int ldk,
                                   char* ldsbase, int tid) {
    const int wave = tid >> 6, lane = tid & 63;
#pragma unroll
    for (int it = 0; it < 2; ++it) {
        const int chunk = wave * 128 + it * 64 + lane;   // 512 chunks of 16B
        const int row = chunk >> 2, s = chunk & 3;
        const char* g = (const char*)(src + (size_t)row * ldk) + ((s ^ ((row >> 1) & 3)) << 4);
        char* l = ldsbase + (size_t)(wave * 2048 + it * 1024);   // wave-uniform base
        __builtin_amdgcn_global_load_lds((const __attribute__((address_space(1))) void*)g,
                                         (__attribute__((address_space(3))) void*)l,
                                         16, 0, 0);
    }
}

__device__ inline bf16x8 frag(const char* ldsbase, int row, int s) {
    return *(const bf16x8*)(ldsbase + row * 64 + ((s ^ ((row >> 1) & 3)) << 4));
}

// ---- fused GCN layer: H = relu(adj * U + bias), adj recomputed on the fly -----
// Grid (2 col-halves, 4 row-tiles, 64 batches) = 512 blocks, 256 thr, 4 waves.
// Per ct (adj col-tile of 128): S = T_r T_ct^T (K=256, 8 steps) -> mask -> Sbuf
// (bf16, [128][136]); then acc += S * Ut_tile (K=128, 2 slots x 2 substeps).
// Rolling 2-slot staging (slot = 16KB), wait vmcnt(0) + raw barrier per consume.
__global__ __launch_bounds__(256, 2) void k_fused(const unsigned short* __restrict__ T_,
                                                  const unsigned short* __restrict__ Ut,
                                                  const float* __restrict__ bias,
                                                  const int* __restrict__ noun,
                                                  unsigned short* __restrict__ H) {
    __shared__ char smem[67584];                 // 2x16KB slots + 34816B Sbuf/bounce
    unsigned short* Sbuf = (unsigned short*)(smem + 32768);
    const int tid = threadIdx.x, lane = tid & 63, wave = tid >> 6;
    const int wr = wave >> 1, wc = wave & 1;
    const int r16 = lane & 15, s = lane >> 4;

    const int nwg = gridDim.x * gridDim.y * gridDim.z;     // 512
    const int wg  = blockIdx.x + gridDim.x * (blockIdx.y + gridDim.y * blockIdx.z);
    const int swz = (wg & 7) * (nwg >> 3) + (wg >> 3);
    const int c0  = swz % gridDim.x;                       // 0..1 output col half
    const int rem = swz / gridDim.x;
    const int ty  = rem % gridDim.y;                       // 0..3 output row tile
    const size_t bz = rem / gridDim.y;

    const unsigned short* Tb = T_ + bz * (size_t)(Nn * Dn);
    const unsigned short* Ar = Tb + (size_t)ty * 128 * Dn;               // A panel rows
    const unsigned short* Ub = Ut + bz * (size_t)(Dn * Nn) + (size_t)c0 * 128 * Nn;
    const int* nm = noun + bz * Nn;

    f32x4 acc[4][4];
#pragma unroll
    for (int m = 0; m < 4; ++m)
#pragma unroll
        for (int n = 0; n < 4; ++n) acc[m][n] = (f32x4){0.f, 0.f, 0.f, 0.f};

    // prologue: slot (ct=0, j=0)
    stage128x32(Ar, Dn, smem,        tid);
    stage128x32(Tb, Dn, smem + 8192, tid);
    int gs = 0;

    for (int ct = 0; ct < 4; ++ct) {
        const unsigned short* Bp = Tb + (size_t)ct * 128 * Dn;
        f32x4 sacc[4][4];
#pragma unroll
        for (int m = 0; m < 4; ++m)
#pragma unroll
            for (int n = 0; n < 4; ++n) sacc[m][n] = (f32x4){0.f, 0.f, 0.f, 0.f};

        for (int j = 0; j < 8; ++j) {                      // S-phase: K=256
            asm volatile("s_waitcnt vmcnt(0)" ::: "memory");
            __builtin_amdgcn_s_barrier();
            __builtin_amdgcn_sched_barrier(0);
            char* nb = smem + 16384 * ((gs + 1) & 1);
            if (j < 7) {
                stage128x32(Ar + (j + 1) * 32, Dn, nb,        tid);
                stage128x32(Bp + (j + 1) * 32, Dn, nb + 8192, tid);
            } else {                                       // U-slot 0 (k-tiles 0,1)
                stage128x32(Ub + ct * 128,      Nn, nb,        tid);
                stage128x32(Ub + ct * 128 + 32, Nn, nb + 8192, tid);
            }
            __builtin_amdgcn_sched_barrier(0);
            const char* cb = smem + 16384 * (gs & 1);
            bf16x8 af[4], bv[4];
#pragma unroll
            for (int m = 0; m < 4; ++m) af[m] = frag(cb,        wr * 64 + m * 16 + r16, s);
#pragma unroll
            for (int n = 0; n < 4; ++n) bv[n] = frag(cb + 8192, wc * 64 + n * 16 + r16, s);
#pragma unroll
            for (int m = 0; m < 4; ++m)
#pragma unroll
                for (int n = 0; n < 4; ++n)
                    sacc[m][n] = __builtin_amdgcn_mfma_f32_16x16x32_bf16(af[m], bv[n], sacc[m][n], 0, 0, 0);
            ++gs;
        }
        // mask S and drop to LDS as bf16 (A-operand layout for U-phase)
#pragma unroll
        for (int n = 0; n < 4; ++n) {
            const int cl = wc * 64 + n * 16 + r16;
            const int c  = ct * 128 + cl;
            const float nmc = (c < IMGn) ? 0.f : (float)nm[c];
#pragma unroll
            for (int m = 0; m < 4; ++m)
#pragma unroll
                for (int i = 0; i < 4; ++i) {
                    const int rl = wr * 64 + m * 16 + s * 4 + i;
                    const int r  = ty * 128 + rl;
                    float mask;
                    if (r < IMGn)      mask = nmc;
                    else if (c < IMGn) mask = (float)nm[r];
                    else               mask = 1.f;
                    Sbuf[rl * 136 + cl] = f2b(sacc[m][n][i] * mask);
                }
        }
        __syncthreads();

        for (int u = 0; u < 2; ++u) {                      // U-phase: K=128
            asm volatile("s_waitcnt vmcnt(0)" ::: "memory");
            __builtin_amdgcn_s_barrier();
            __builtin_amdgcn_sched_barrier(0);
            char* nb = smem + 16384 * ((gs + 1) & 1);
            if (u == 0) {                                  // U-slot 1 (k-tiles 2,3)
                stage128x32(Ub + ct * 128 + 64, Nn, nb,        tid);
                stage128x32(Ub + ct * 128 + 96, Nn, nb + 8192, tid);
            } else if (ct < 3) {                           // next ct, S j=0
                stage128x32(Ar,                      Dn, nb,        tid);
                stage128x32(Tb + (ct + 1) * 128 * Dn, Dn, nb + 8192, tid);
            }
            __builtin_amdgcn_sched_barrier(0);
            const char* cb = smem + 16384 * (gs & 1);
#pragma unroll
            for (int h = 0; h < 2; ++h) {
                const int kk = u * 2 + h;
                bf16x8 af[4], bv[4];
#pragma unroll
                for (int m = 0; m < 4; ++m)
                    af[m] = *(const bf16x8*)((const char*)Sbuf +
                              (size_t)(wr * 64 + m * 16 + r16) * 272 + kk * 64 + s * 16);
#pragma unroll
                for (int n = 0; n < 4; ++n) bv[n] = frag(cb + h * 8192, wc * 64 + n * 16 + r16, s);
#pragma unroll
                for (int m = 0; m < 4; ++m)
#pragma unroll
                    for (int n = 0; n < 4; ++n)
                        acc[m][n] = __builtin_amdgcn_mfma_f32_16x16x32_bf16(af[m], bv[n], acc[m][n], 0, 0, 0);
            }
            ++gs;
        }
    }

    // epilogue: bias + relu -> bf16, bounce through LDS, coalesced store
    __syncthreads();
#pragma unroll
    for (int n = 0; n < 4; ++n) {
        const int cl = wc * 64 + n * 16 + r16;
        const float bvv = bias[c0 * 128 + cl];
#pragma unroll
        for (int m = 0; m < 4; ++m)
#pragma unroll
            for (int i = 0; i < 4; ++i) {
                const int rl = wr * 64 + m * 16 + s * 4 + i;
                Sbuf[rl * 136 + cl] = f2b(fmaxf(acc[m][n][i] + bvv, 0.f));
            }
    }
    __syncthreads();
    const int row = tid >> 1, h = tid & 1;
    unsigned short* out = H + bz * (size_t)(Nn * Dn);
    const bf16x8* srcv = (const bf16x8*)(Sbuf + (size_t)row * 136 + h * 64);
    bf16x8* dstv = (bf16x8*)(out + (size_t)(ty * 128 + row) * Dn + c0 * 128 + h * 64);
#pragma unroll
    for (int q = 0; q < 8; ++q) dstv[q] = srcv[q];
}

// ---- generic MFMA GEMM (TRANS / FINAL epilogues), 3-buffer counted vmcnt ------
enum { EPI_TRANS = 1, EPI_FINAL = 3 };

template<int EPI>
__global__ __launch_bounds__(256) void k_mfma(const unsigned short* __restrict__ Abase,
                                              const unsigned short* __restrict__ Bbase,
                                              void* __restrict__ outp,
                                              const float* __restrict__ bias,
                                              int K, int lda, int ldb) {
    extern __shared__ char smem[];
    const int tid = threadIdx.x, lane = tid & 63, wave = tid >> 6;
    const int wr = wave >> 1, wc = wave & 1;
    const int r16 = lane & 15, s = lane >> 4;

    const int nwg = gridDim.x * gridDim.y * gridDim.z;
    const int wg  = blockIdx.x + gridDim.x * (blockIdx.y + gridDim.y * blockIdx.z);
    const int swz = (wg & 7) * (nwg >> 3) + (wg >> 3);
    const int tile_x = swz % gridDim.x;
    const int rem    = swz / gridDim.x;
    const int tile_y = rem % gridDim.y;

    const unsigned short* A  = Abase + (size_t)tile_y * 128 * lda;
    const unsigned short* Bt = Bbase + (size_t)tile_x * 128 * ldb;

    f32x4 acc[4][4];
#pragma unroll
    for (int m = 0; m < 4; ++m)
#pragma unroll
        for (int n = 0; n < 4; ++n) acc[m][n] = (f32x4){0.f, 0.f, 0.f, 0.f};

    const int NT = K >> 5;
    stage128x32(A,       lda, smem,                tid);
    stage128x32(Bt,      ldb, smem + 8192,         tid);
    stage128x32(A + 32,  lda, smem + 16384,        tid);
    stage128x32(Bt + 32, ldb, smem + 16384 + 8192, tid);
    for (int t = 0; t < NT; ++t) {
        if (t < NT - 1) { asm volatile("s_waitcnt vmcnt(4)" ::: "memory"); }
        else            { asm volatile("s_waitcnt vmcnt(0)" ::: "memory"); }
        __builtin_amdgcn_s_barrier();
        __builtin_amdgcn_sched_barrier(0);
        if (t + 2 < NT) {
            char* nb = smem + 16384 * ((t + 2) % 3);
            stage128x32(A  + (t + 2) * 32, lda, nb,        tid);
            stage128x32(Bt + (t + 2) * 32, ldb, nb + 8192, tid);
        }
        __builtin_amdgcn_sched_barrier(0);
        const char* cb = smem + 16384 * (t % 3);
        bf16x8 af[4], bv[4];
#pragma unroll
        for (int m = 0; m < 4; ++m) af[m] = frag(cb,        wr * 64 + m * 16 + r16, s);
#pragma unroll
        for (int n = 0; n < 4; ++n) bv[n] = frag(cb + 8192, wc * 64 + n * 16 + r16, s);
#pragma unroll
        for (int m = 0; m < 4; ++m)
#pragma unroll
            for (int n = 0; n < 4; ++n)
                acc[m][n] = __builtin_amdgcn_mfma_f32_16x16x32_bf16(af[m], bv[n], acc[m][n], 0, 0, 0);
    }
    __syncthreads();

    const int row0 = tile_y * 128, col0 = tile_x * 128;
    unsigned short* lt = (unsigned short*)smem;
    const int row = tid >> 1, h = tid & 1;

    if constexpr (EPI == EPI_FINAL) {
        float* lt32 = (float*)smem;
        float* out = (float*)outp;
#pragma unroll
        for (int p = 0; p < 2; ++p) {
            if (p) __syncthreads();
            if (wc == p) {
#pragma unroll
                for (int n = 0; n < 4; ++n) {
                    const int cll = n * 16 + r16;
                    const float bvv = bias[col0 + p * 64 + cll];
#pragma unroll
                    for (int m = 0; m < 4; ++m)
#pragma unroll
                        for (int i = 0; i < 4; ++i) {
                            const int rl = wr * 64 + m * 16 + s * 4 + i;
                            lt32[rl * 68 + cll] = fmaxf(acc[m][n][i] + bvv, 0.f);
                        }
                }
            }
            __syncthreads();
            const float4* srcv = (const float4*)(lt32 + (size_t)row * 68 + h * 32);
            float4* dstv = (float4*)(out + (size_t)(row0 + row) * Dn + col0 + p * 64 + h * 32);
#pragma unroll
            for (int q = 0; q < 8; ++q) dstv[q] = srcv[q];
        }
    } else {  // EPI_TRANS: out Ut[b][c][r_local], via padded-LDS transpose bounce
#pragma unroll
        for (int n = 0; n < 4; ++n)
#pragma unroll
            for (int m = 0; m < 4; ++m)
#pragma unroll
                for (int i = 0; i < 4; ++i) {
                    const int ct = wc * 64 + n * 16 + r16;
                    const int rt = wr * 64 + m * 16 + s * 4 + i;
                    lt[ct * 136 + rt] = f2b(acc[m][n][i]);
                }
        __syncthreads();
        const int bm = tile_y;
        const size_t bb = bm >> 2;
        const int rl0 = (bm & 3) * 128;
        unsigned short* out = (unsigned short*)outp + bb * ((size_t)Dn * Nn);
        const int ctc = tid >> 1;
        const bf16x8* srcv = (const bf16x8*)(lt + (size_t)ctc * 136 + h * 64);
        bf16x8* dstv = (bf16x8*)(out + (size_t)(col0 + ctc) * Nn + rl0 + h * 64);
#pragma unroll
        for (int q = 0; q < 8; ++q) dstv[q] = srcv[q];
    }
}

extern "C" void kernel_launch(void* const* d_in, const int* in_sizes, int n_in,
                              void* d_out, int out_size, void* d_ws, size_t ws_size,
                              hipStream_t stream) {
    const float* input_1 = (const float*)d_in[0];
    const float* input_2 = (const float*)d_in[1];
    const int*   noun    = (const int*)d_in[3];
    const float* w0 = (const float*)d_in[4];
    const float* b0 = (const float*)d_in[5];
    const float* w1 = (const float*)d_in[6];
    const float* b1 = (const float*)d_in[7];
    const float* wf = (const float*)d_in[8];
    const float* bf = (const float*)d_in[9];

    unsigned short* ws  = (unsigned short*)d_ws;
    unsigned short* T   = ws;                    // 64*512*256
    unsigned short* A0  = ws +  8388608;         // input_1 bf16
    unsigned short* Ut  = ws + 16777216;         // 64*256*512
    unsigned short* H1  = ws + 25165824;
    unsigned short* H2  = ws + 33554432;
    unsigned short* w0b = ws + 41943040;
    unsigned short* w1b = w0b + 65536;
    unsigned short* wfb = w1b + 65536;

    dim3 blk(256);
    k_prep<<<10432, blk, 0, stream>>>(input_1, input_2, w0, w1, wf, A0, T, w0b, w1b, wfb);

    // Ut0 = (input_1 @ w0^T)^T                   M=32768 flat, N=256, K=256
    k_mfma<EPI_TRANS><<<dim3(2, 256, 1), blk, 49152, stream>>>(
        A0, w0b, Ut, nullptr, 256, 256, 256);
    // H1 = relu(adj @ U0 + b0), adj recomputed from T
    k_fused<<<dim3(2, 4, Bn), blk, 0, stream>>>(T, Ut, b0, noun, H1);
    // Ut1 = (H1 @ w1^T)^T
    k_mfma<EPI_TRANS><<<dim3(2, 256, 1), blk, 49152, stream>>>(
        H1, w1b, Ut, nullptr, 256, 256, 256);
    // H2 = relu(adj @ U1 + b1)
    k_fused<<<dim3(2, 4, Bn), blk, 0, stream>>>(T, Ut, b1, noun, H2);
    // out = relu(H2 @ wf^T + bf)  (fp32 out)
    k_mfma<EPI_FINAL><<<dim3(2, 256, 1), blk, 49152, stream>>>(
        H2, wfb, d_out, bf, 256, 256, 256);
}

// Round 9
// 128.128 us; speedup vs baseline: 1.3013x; 1.3013x over previous
//
#include <hip/hip_runtime.h>
#include <math.h>

#define Bn   64
#define Nn   512
#define Dn   256
#define IMGn 51

typedef __attribute__((ext_vector_type(8))) short bf16x8;
typedef __attribute__((ext_vector_type(4))) float f32x4;
typedef __attribute__((ext_vector_type(4))) unsigned short u16x4;

__device__ inline unsigned short f2b(float f) {            // fp32 -> bf16 RNE
    union { float f; unsigned u; } v; v.f = f;
    unsigned r = v.u + 0x7fffu + ((v.u >> 16) & 1u);
    return (unsigned short)(r >> 16);
}

// ---- fused prep: l2norm(input_2)->T, cvt(input_1)->A0, cvt weights ------------
// Remapped so each batch's outputs are produced on its consumer XCD (id&7).
__global__ __launch_bounds__(256) void k_prep(const float* __restrict__ in1,
                                              const float* __restrict__ in2,
                                              const float* __restrict__ w0,
                                              const float* __restrict__ w1,
                                              const float* __restrict__ wf,
                                              unsigned short* __restrict__ A0,
                                              unsigned short* __restrict__ T,
                                              unsigned short* __restrict__ w0b,
                                              unsigned short* __restrict__ w1b,
                                              unsigned short* __restrict__ wfb) {
    const int bid = blockIdx.x, tid = threadIdx.x;
    if (bid < 8192) {                                      // norm: 4 rows/block
        const int xcd = bid & 7, j = bid >> 3;
        const int b = xcd * 8 + (j >> 7), rb = j & 127;
        const int row = b * 512 + rb * 4 + (tid >> 6);
        const int lane = tid & 63;
        float4 v = ((const float4*)(in2 + (size_t)row * Dn))[lane];
        float ss = v.x * v.x + v.y * v.y + v.z * v.z + v.w * v.w;
#pragma unroll
        for (int m = 1; m < 64; m <<= 1) ss += __shfl_xor(ss, m);
        float inv = 1.0f / fmaxf(sqrtf(ss), 1e-8f);
        u16x4 o = { f2b(v.x*inv), f2b(v.y*inv), f2b(v.z*inv), f2b(v.w*inv) };
        ((u16x4*)(T + (size_t)row * Dn))[lane] = o;
    } else if (bid < 10240) {                              // cvt input_1
        const int id2 = bid - 8192;
        const int xcd = id2 & 7, j = id2 >> 3;
        const int b = xcd * 8 + (j >> 5), jj = j & 31;
        int i = b * 32768 + jj * 1024 + tid;
#pragma unroll
        for (int q = 0; q < 4; ++q, i += 256) {
            float4 v = ((const float4*)in1)[i];
            u16x4 o = { f2b(v.x), f2b(v.y), f2b(v.z), f2b(v.w) };
            ((u16x4*)A0)[i] = o;
        }
    } else {                                               // cvt weights
        const int b2 = bid - 10240;
        const float* src = (b2 < 64) ? w0 : (b2 < 128) ? w1 : wf;
        unsigned short* dst = (b2 < 64) ? w0b : (b2 < 128) ? w1b : wfb;
        const int i = (b2 & 63) * 256 + tid;
        float4 v = ((const float4*)src)[i];
        u16x4 o = { f2b(v.x), f2b(v.y), f2b(v.z), f2b(v.w) };
        ((u16x4*)dst)[i] = o;
    }
}

// ---- staging / fragment helpers ----------------------------------------------
// LDS: 2 slots of 17408B each (A 8KB @0, B 8KB @8192, 1KB pad).
// Epilogue bounce reuses smem[0..34816) contiguously.
__device__ inline void stage128x32(const unsigned short* __restrict__ src, int ldk,
                                   char* ldsbase, int tid) {
    const int wave = tid >> 6, lane = tid & 63;
#pragma unroll
    for (int it = 0; it < 2; ++it) {
        const int chunk = wave * 128 + it * 64 + lane;   // 512 chunks of 16B
        const int row = chunk >> 2, s = chunk & 3;
        const char* g = (const char*)(src + (size_t)row * ldk) + ((s ^ ((row >> 1) & 3)) << 4);
        char* l = ldsbase + (size_t)(wave * 2048 + it * 1024);   // wave-uniform base
        __builtin_amdgcn_global_load_lds((const __attribute__((address_space(1))) void*)g,
                                         (__attribute__((address_space(3))) void*)l,
                                         16, 0, 0);
    }
}

__device__ inline bf16x8 frag(const char* ldsbase, int row, int s) {
    return *(const bf16x8*)(ldsbase + row * 64 + ((s ^ ((row >> 1) & 3)) << 4));
}

// ---- R4-proven drain-style 2-buffer GEMM main loop (low VGPR) -----------------
__device__ inline void gemm_loop(const unsigned short* __restrict__ A,
                                 const unsigned short* __restrict__ Bt,
                                 int lda, int ldb, int NT, char* smem, int tid,
                                 int wr, int wc, int r16, int s, f32x4 (&acc)[4][4]) {
#pragma unroll
    for (int m = 0; m < 4; ++m)
#pragma unroll
        for (int n = 0; n < 4; ++n) acc[m][n] = (f32x4){0.f, 0.f, 0.f, 0.f};
    stage128x32(A,  lda, smem,        tid);
    stage128x32(Bt, ldb, smem + 8192, tid);
    __syncthreads();
    for (int t = 0; t < NT; ++t) {
        if (t + 1 < NT) {
            char* nb = smem + 17408 * ((t + 1) & 1);
            stage128x32(A  + (t + 1) * 32, lda, nb,        tid);
            stage128x32(Bt + (t + 1) * 32, ldb, nb + 8192, tid);
        }
        const char* cb = smem + 17408 * (t & 1);
        bf16x8 af[4], bv[4];
#pragma unroll
        for (int m = 0; m < 4; ++m) af[m] = frag(cb,        wr * 64 + m * 16 + r16, s);
#pragma unroll
        for (int n = 0; n < 4; ++n) bv[n] = frag(cb + 8192, wc * 64 + n * 16 + r16, s);
#pragma unroll
        for (int m = 0; m < 4; ++m)
#pragma unroll
            for (int n = 0; n < 4; ++n)
                acc[m][n] = __builtin_amdgcn_mfma_f32_16x16x32_bf16(af[m], bv[n], acc[m][n], 0, 0, 0);
        __syncthreads();
    }
}

// ---- merged GRAM (1024 blocks) + TRANS1 (512 blocks) --------------------------
__global__ __launch_bounds__(256, 4) void k_gt(const unsigned short* __restrict__ T_,
                                               const unsigned short* __restrict__ A0,
                                               const unsigned short* __restrict__ w0b,
                                               const int* __restrict__ noun,
                                               unsigned short* __restrict__ adj,
                                               unsigned short* __restrict__ Ut) {
    __shared__ char smem[34816];
    const int tid = threadIdx.x, lane = tid & 63, wave = tid >> 6;
    const int wr = wave >> 1, wc = wave & 1;
    const int r16 = lane & 15, s = lane >> 4;
    const int id = blockIdx.x, xcd = id & 7, gid = id >> 3;   // gid 0..191
    f32x4 acc[4][4];

    if (gid < 128) {                                       // ---- GRAM ----
        const int b = xcd * 8 + (gid >> 4);
        const int tile = gid & 15, bx = tile & 3, by = tile >> 2;
        const unsigned short* Tb = T_ + (size_t)b * Nn * Dn;
        gemm_loop(Tb + (size_t)by * 128 * Dn, Tb + (size_t)bx * 128 * Dn,
                  Dn, Dn, 8, smem, tid, wr, wc, r16, s, acc);
        const int row0 = by * 128, col0 = bx * 128;
        const int* nm = noun + b * Nn;
        unsigned short* lt = (unsigned short*)smem;        // [128][136]
#pragma unroll
        for (int n = 0; n < 4; ++n) {
            const int cl = wc * 64 + n * 16 + r16;
            const int c  = col0 + cl;
            const float nmc = (c < IMGn) ? 0.f : (float)nm[c];
#pragma unroll
            for (int m = 0; m < 4; ++m)
#pragma unroll
                for (int i = 0; i < 4; ++i) {
                    const int rl = wr * 64 + m * 16 + s * 4 + i;
                    const int r  = row0 + rl;
                    float mask;
                    if (r < IMGn)      mask = nmc;
                    else if (c < IMGn) mask = (float)nm[r];
                    else               mask = 1.f;
                    lt[rl * 136 + cl] = f2b(acc[m][n][i] * mask);
                }
        }
        __syncthreads();
        unsigned short* out = adj + (size_t)b * Nn * Nn;
        const int row = tid >> 1, h = tid & 1;
        const bf16x8* srcv = (const bf16x8*)(lt + (size_t)row * 136 + h * 64);
        bf16x8* dstv = (bf16x8*)(out + (size_t)(row0 + row) * Nn + col0 + h * 64);
#pragma unroll
        for (int q = 0; q < 8; ++q) dstv[q] = srcv[q];
    } else {                                               // ---- TRANS1 ----
        const int idx = xcd * 64 + (gid - 128);            // 0..511
        const int tx = idx & 1, ty = idx >> 1;
        gemm_loop(A0 + (size_t)ty * 128 * Dn, w0b + (size_t)tx * 128 * Dn,
                  Dn, Dn, 8, smem, tid, wr, wc, r16, s, acc);
        unsigned short* lt = (unsigned short*)smem;
#pragma unroll
        for (int n = 0; n < 4; ++n)
#pragma unroll
            for (int m = 0; m < 4; ++m)
#pragma unroll
                for (int i = 0; i < 4; ++i) {
                    const int ct = wc * 64 + n * 16 + r16;
                    const int rt = wr * 64 + m * 16 + s * 4 + i;
                    lt[ct * 136 + rt] = f2b(acc[m][n][i]);
                }
        __syncthreads();
        const size_t bb = ty >> 2;
        const int rl0 = (ty & 3) * 128, col0 = tx * 128;
        unsigned short* out = Ut + bb * ((size_t)Dn * Nn);
        const int ct = tid >> 1, h = tid & 1;
        const bf16x8* srcv = (const bf16x8*)(lt + (size_t)ct * 136 + h * 64);
        bf16x8* dstv = (bf16x8*)(out + (size_t)(col0 + ct) * Nn + rl0 + h * 64);
#pragma unroll
        for (int q = 0; q < 8; ++q) dstv[q] = srcv[q];
    }
}

// ---- H = relu(adj @ Ut^T + bias) (512 blocks) ---------------------------------
__global__ __launch_bounds__(256, 4) void k_biash(const unsigned short* __restrict__ adj,
                                                  const unsigned short* __restrict__ Ut,
                                                  const float* __restrict__ bias,
                                                  unsigned short* __restrict__ H) {
    __shared__ char smem[34816];
    const int tid = threadIdx.x, lane = tid & 63, wave = tid >> 6;
    const int wr = wave >> 1, wc = wave & 1;
    const int r16 = lane & 15, s = lane >> 4;
    const int id = blockIdx.x, xcd = id & 7, gid = id >> 3;   // gid 0..63
    const int b = xcd * 8 + (gid >> 3);
    const int tile = gid & 7, tx = tile & 1, ty = tile >> 1;
    f32x4 acc[4][4];
    gemm_loop(adj + (size_t)b * Nn * Nn + (size_t)ty * 128 * Nn,
              Ut  + (size_t)b * Dn * Nn + (size_t)tx * 128 * Nn,
              Nn, Nn, 16, smem, tid, wr, wc, r16, s, acc);
    const int row0 = ty * 128, col0 = tx * 128;
    unsigned short* lt = (unsigned short*)smem;
#pragma unroll
    for (int n = 0; n < 4; ++n) {
        const int cl = wc * 64 + n * 16 + r16;
        const float bvv = bias[col0 + cl];
#pragma unroll
        for (int m = 0; m < 4; ++m)
#pragma unroll
            for (int i = 0; i < 4; ++i) {
                const int rl = wr * 64 + m * 16 + s * 4 + i;
                lt[rl * 136 + cl] = f2b(fmaxf(acc[m][n][i] + bvv, 0.f));
            }
    }
    __syncthreads();
    unsigned short* out = H + (size_t)b * Nn * Dn;
    const int row = tid >> 1, h = tid & 1;
    const bf16x8* srcv = (const bf16x8*)(lt + (size_t)row * 136 + h * 64);
    bf16x8* dstv = (bf16x8*)(out + (size_t)(row0 + row) * Dn + col0 + h * 64);
#pragma unroll
    for (int q = 0; q < 8; ++q) dstv[q] = srcv[q];
}

// ---- Ut = (Hin @ W^T)^T (512 blocks) ------------------------------------------
__global__ __launch_bounds__(256, 4) void k_trans(const unsigned short* __restrict__ Hin,
                                                  const unsigned short* __restrict__ Wb,
                                                  unsigned short* __restrict__ Ut) {
    __shared__ char smem[34816];
    const int tid = threadIdx.x, lane = tid & 63, wave = tid >> 6;
    const int wr = wave >> 1, wc = wave & 1;
    const int r16 = lane & 15, s = lane >> 4;
    const int id = blockIdx.x, xcd = id & 7;
    const int idx = xcd * 64 + (id >> 3);
    const int tx = idx & 1, ty = idx >> 1;
    f32x4 acc[4][4];
    gemm_loop(Hin + (size_t)ty * 128 * Dn, Wb + (size_t)tx * 128 * Dn,
              Dn, Dn, 8, smem, tid, wr, wc, r16, s, acc);
    unsigned short* lt = (unsigned short*)smem;
#pragma unroll
    for (int n = 0; n < 4; ++n)
#pragma unroll
        for (int m = 0; m < 4; ++m)
#pragma unroll
            for (int i = 0; i < 4; ++i) {
                const int ct = wc * 64 + n * 16 + r16;
                const int rt = wr * 64 + m * 16 + s * 4 + i;
                lt[ct * 136 + rt] = f2b(acc[m][n][i]);
            }
    __syncthreads();
    const size_t bb = ty >> 2;
    const int rl0 = (ty & 3) * 128, col0 = tx * 128;
    unsigned short* out = Ut + bb * ((size_t)Dn * Nn);
    const int ct = tid >> 1, h = tid & 1;
    const bf16x8* srcv = (const bf16x8*)(lt + (size_t)ct * 136 + h * 64);
    bf16x8* dstv = (bf16x8*)(out + (size_t)(col0 + ct) * Nn + rl0 + h * 64);
#pragma unroll
    for (int q = 0; q < 8; ++q) dstv[q] = srcv[q];
}

// ---- out = relu(H2 @ wf^T + bf), fp32 (512 blocks) ----------------------------
__global__ __launch_bounds__(256, 4) void k_final(const unsigned short* __restrict__ H2,
                                                  const unsigned short* __restrict__ wfb,
                                                  const float* __restrict__ bias,
                                                  float* __restrict__ out) {
    __shared__ char smem[34816];
    const int tid = threadIdx.x, lane = tid & 63, wave = tid >> 6;
    const int wr = wave >> 1, wc = wave & 1;
    const int r16 = lane & 15, s = lane >> 4;
    const int id = blockIdx.x, xcd = id & 7;
    const int idx = xcd * 64 + (id >> 3);
    const int tx = idx & 1, ty = idx >> 1;
    f32x4 acc[4][4];
    gemm_loop(H2 + (size_t)ty * 128 * Dn, wfb + (size_t)tx * 128 * Dn,
              Dn, Dn, 8, smem, tid, wr, wc, r16, s, acc);
    const int row0 = ty * 128, col0 = tx * 128;
    float* lt32 = (float*)smem;                            // [128][68]
    const int row = tid >> 1, h = tid & 1;
#pragma unroll
    for (int p = 0; p < 2; ++p) {
        if (p) __syncthreads();
        if (wc == p) {
#pragma unroll
            for (int n = 0; n < 4; ++n) {
                const int cll = n * 16 + r16;
                const float bvv = bias[col0 + p * 64 + cll];
#pragma unroll
                for (int m = 0; m < 4; ++m)
#pragma unroll
                    for (int i = 0; i < 4; ++i) {
                        const int rl = wr * 64 + m * 16 + s * 4 + i;
                        lt32[rl * 68 + cll] = fmaxf(acc[m][n][i] + bvv, 0.f);
                    }
            }
        }
        __syncthreads();
        const float4* srcv = (const float4*)(lt32 + (size_t)row * 68 + h * 32);
        float4* dstv = (float4*)(out + (size_t)(row0 + row) * Dn + col0 + p * 64 + h * 32);
#pragma unroll
        for (int q = 0; q < 8; ++q) dstv[q] = srcv[q];
    }
}

extern "C" void kernel_launch(void* const* d_in, const int* in_sizes, int n_in,
                              void* d_out, int out_size, void* d_ws, size_t ws_size,
                              hipStream_t stream) {
    const float* input_1 = (const float*)d_in[0];
    const float* input_2 = (const float*)d_in[1];
    const int*   noun    = (const int*)d_in[3];
    const float* w0 = (const float*)d_in[4];
    const float* b0 = (const float*)d_in[5];
    const float* w1 = (const float*)d_in[6];
    const float* b1 = (const float*)d_in[7];
    const float* wf = (const float*)d_in[8];
    const float* bf = (const float*)d_in[9];

    unsigned short* ws  = (unsigned short*)d_ws;
    unsigned short* T   = ws;                    // 64*512*256
    unsigned short* A0  = ws +  8388608;         // input_1 bf16
    unsigned short* adj = ws + 16777216;         // 64*512*512
    unsigned short* Ut  = ws + 33554432;         // 64*256*512
    unsigned short* H1  = ws + 41943040;
    unsigned short* H2  = ws + 50331648;
    unsigned short* w0b = ws + 58720256;
    unsigned short* w1b = w0b + 65536;
    unsigned short* wfb = w1b + 65536;

    dim3 blk(256);
    k_prep<<<10432, blk, 0, stream>>>(input_1, input_2, w0, w1, wf, A0, T, w0b, w1b, wfb);
    // GRAM (adj) + TRANS1 (Ut0) merged
    k_gt<<<1536, blk, 0, stream>>>(T, A0, w0b, noun, adj, Ut);
    // H1 = relu(adj @ Ut0^T + b0)
    k_biash<<<512, blk, 0, stream>>>(adj, Ut, b0, H1);
    // Ut1 = (H1 @ w1^T)^T
    k_trans<<<512, blk, 0, stream>>>(H1, w1b, Ut);
    // H2 = relu(adj @ Ut1^T + b1)
    k_biash<<<512, blk, 0, stream>>>(adj, Ut, b1, H2);
    // out = relu(H2 @ wf^T + bf)
    k_final<<<512, blk, 0, stream>>>(H2, wfb, bf, (float*)d_out);
}

// Round 10
// 124.900 us; speedup vs baseline: 1.3349x; 1.0258x over previous
//
#include <hip/hip_runtime.h>
#include <math.h>

#define Bn   64
#define Nn   512
#define Dn   256
#define IMGn 51

typedef __attribute__((ext_vector_type(8))) short bf16x8;
typedef __attribute__((ext_vector_type(4))) float f32x4;
typedef __attribute__((ext_vector_type(4))) unsigned short u16x4;

__device__ inline unsigned short f2b(float f) {            // fp32 -> bf16 RNE
    union { float f; unsigned u; } v; v.f = f;
    unsigned r = v.u + 0x7fffu + ((v.u >> 16) & 1u);
    return (unsigned short)(r >> 16);
}

// ---- fused prep: l2norm(input_2)->T, cvt(input_1)->A0, cvt weights ------------
// Remapped so each batch's outputs are produced on its consumer XCD (id&7).
__global__ __launch_bounds__(256) void k_prep(const float* __restrict__ in1,
                                              const float* __restrict__ in2,
                                              const float* __restrict__ w0,
                                              const float* __restrict__ w1,
                                              const float* __restrict__ wf,
                                              unsigned short* __restrict__ A0,
                                              unsigned short* __restrict__ T,
                                              unsigned short* __restrict__ w0b,
                                              unsigned short* __restrict__ w1b,
                                              unsigned short* __restrict__ wfb) {
    const int bid = blockIdx.x, tid = threadIdx.x;
    if (bid < 8192) {                                      // norm: 4 rows/block
        const int xcd = bid & 7, j = bid >> 3;
        const int b = xcd * 8 + (j >> 7), rb = j & 127;
        const int row = b * 512 + rb * 4 + (tid >> 6);
        const int lane = tid & 63;
        float4 v = ((const float4*)(in2 + (size_t)row * Dn))[lane];
        float ss = v.x * v.x + v.y * v.y + v.z * v.z + v.w * v.w;
#pragma unroll
        for (int m = 1; m < 64; m <<= 1) ss += __shfl_xor(ss, m);
        float inv = 1.0f / fmaxf(sqrtf(ss), 1e-8f);
        u16x4 o = { f2b(v.x*inv), f2b(v.y*inv), f2b(v.z*inv), f2b(v.w*inv) };
        ((u16x4*)(T + (size_t)row * Dn))[lane] = o;
    } else if (bid < 10240) {                              // cvt input_1
        const int id2 = bid - 8192;
        const int xcd = id2 & 7, j = id2 >> 3;
        const int b = xcd * 8 + (j >> 5), jj = j & 31;
        int i = b * 32768 + jj * 1024 + tid;
#pragma unroll
        for (int q = 0; q < 4; ++q, i += 256) {
            float4 v = ((const float4*)in1)[i];
            u16x4 o = { f2b(v.x), f2b(v.y), f2b(v.z), f2b(v.w) };
            ((u16x4*)A0)[i] = o;
        }
    } else {                                               // cvt weights
        const int b2 = bid - 10240;
        const float* src = (b2 < 64) ? w0 : (b2 < 128) ? w1 : wf;
        unsigned short* dst = (b2 < 64) ? w0b : (b2 < 128) ? w1b : wfb;
        const int i = (b2 & 63) * 256 + tid;
        float4 v = ((const float4*)src)[i];
        u16x4 o = { f2b(v.x), f2b(v.y), f2b(v.z), f2b(v.w) };
        ((u16x4*)dst)[i] = o;
    }
}

// ---- staging / fragment helpers ----------------------------------------------
// LDS: 2 slots of 17408B each (A 8KB @0, B 8KB @8192, 1KB pad).
// Epilogue bounce reuses smem[0..34816) contiguously.
__device__ inline void stage128x32(const unsigned short* __restrict__ src, int ldk,
                                   char* ldsbase, int tid) {
    const int wave = tid >> 6, lane = tid & 63;
#pragma unroll
    for (int it = 0; it < 2; ++it) {
        const int chunk = wave * 128 + it * 64 + lane;   // 512 chunks of 16B
        const int row = chunk >> 2, s = chunk & 3;
        const char* g = (const char*)(src + (size_t)row * ldk) + ((s ^ ((row >> 1) & 3)) << 4);
        char* l = ldsbase + (size_t)(wave * 2048 + it * 1024);   // wave-uniform base
        __builtin_amdgcn_global_load_lds((const __attribute__((address_space(1))) void*)g,
                                         (__attribute__((address_space(3))) void*)l,
                                         16, 0, 0);
    }
}

__device__ inline bf16x8 frag(const char* ldsbase, int row, int s) {
    return *(const bf16x8*)(ldsbase + row * 64 + ((s ^ ((row >> 1) & 3)) << 4));
}

// ---- R4-proven drain-style 2-buffer GEMM main loop (low VGPR) -----------------
__device__ inline void gemm_loop(const unsigned short* __restrict__ A,
                                 const unsigned short* __restrict__ Bt,
                                 int lda, int ldb, int NT, char* smem, int tid,
                                 int wr, int wc, int r16, int s, f32x4 (&acc)[4][4]) {
#pragma unroll
    for (int m = 0; m < 4; ++m)
#pragma unroll
        for (int n = 0; n < 4; ++n) acc[m][n] = (f32x4){0.f, 0.f, 0.f, 0.f};
    stage128x32(A,  lda, smem,        tid);
    stage128x32(Bt, ldb, smem + 8192, tid);
    __syncthreads();
    for (int t = 0; t < NT; ++t) {
        if (t + 1 < NT) {
            char* nb = smem + 17408 * ((t + 1) & 1);
            stage128x32(A  + (t + 1) * 32, lda, nb,        tid);
            stage128x32(Bt + (t + 1) * 32, ldb, nb + 8192, tid);
        }
        const char* cb = smem + 17408 * (t & 1);
        bf16x8 af[4], bv[4];
#pragma unroll
        for (int m = 0; m < 4; ++m) af[m] = frag(cb,        wr * 64 + m * 16 + r16, s);
#pragma unroll
        for (int n = 0; n < 4; ++n) bv[n] = frag(cb + 8192, wc * 64 + n * 16 + r16, s);
#pragma unroll
        for (int m = 0; m < 4; ++m)
#pragma unroll
            for (int n = 0; n < 4; ++n)
                acc[m][n] = __builtin_amdgcn_mfma_f32_16x16x32_bf16(af[m], bv[n], acc[m][n], 0, 0, 0);
        __syncthreads();
    }
}

// ---- merged GRAM upper-tri (640 blocks, mirror-stored) + TRANS1 (512) ---------
__global__ __launch_bounds__(256, 4) void k_gt(const unsigned short* __restrict__ T_,
                                               const unsigned short* __restrict__ A0,
                                               const unsigned short* __restrict__ w0b,
                                               const int* __restrict__ noun,
                                               unsigned short* __restrict__ adj,
                                               unsigned short* __restrict__ Ut) {
    __shared__ char smem[34816];
    const int tid = threadIdx.x, lane = tid & 63, wave = tid >> 6;
    const int wr = wave >> 1, wc = wave & 1;
    const int r16 = lane & 15, s = lane >> 4;
    const int id = blockIdx.x, xcd = id & 7, gid = id >> 3;   // gid 0..143
    f32x4 acc[4][4];

    if (gid < 80) {                                        // ---- GRAM (10 tiles) ----
        const int b = xcd * 8 + (gid & 7);
        const int tile = gid >> 3;                         // 0..9 upper-tri
        int ty_, tx_;
        if (tile < 4)      { ty_ = 0; tx_ = tile; }
        else if (tile < 7) { ty_ = 1; tx_ = tile - 3; }
        else if (tile < 9) { ty_ = 2; tx_ = tile - 5; }
        else               { ty_ = 3; tx_ = 3; }
        const unsigned short* Tb = T_ + (size_t)b * Nn * Dn;
        gemm_loop(Tb + (size_t)ty_ * 128 * Dn, Tb + (size_t)tx_ * 128 * Dn,
                  Dn, Dn, 8, smem, tid, wr, wc, r16, s, acc);
        const int row0 = ty_ * 128, col0 = tx_ * 128;
        const int* nm = noun + b * Nn;
        unsigned short* out = adj + (size_t)b * Nn * Nn;
        unsigned short* lt = (unsigned short*)smem;        // [128][136]
        const int row = tid >> 1, h = tid & 1;
#pragma unroll
        for (int n = 0; n < 4; ++n) {
            const int cl = wc * 64 + n * 16 + r16;
            const int c  = col0 + cl;
            const float nmc = (c < IMGn) ? 0.f : (float)nm[c];
#pragma unroll
            for (int m = 0; m < 4; ++m)
#pragma unroll
                for (int i = 0; i < 4; ++i) {
                    const int rl = wr * 64 + m * 16 + s * 4 + i;
                    const int r  = row0 + rl;
                    float mask;
                    if (r < IMGn)      mask = nmc;
                    else if (c < IMGn) mask = (float)nm[r];
                    else               mask = 1.f;
                    lt[rl * 136 + cl] = f2b(acc[m][n][i] * mask);
                }
        }
        __syncthreads();
        {
            const bf16x8* srcv = (const bf16x8*)(lt + (size_t)row * 136 + h * 64);
            bf16x8* dstv = (bf16x8*)(out + (size_t)(row0 + row) * Nn + col0 + h * 64);
#pragma unroll
            for (int q = 0; q < 8; ++q) dstv[q] = srcv[q];
        }
        if (tx_ != ty_) {                                  // mirror tile (adj symmetric)
            __syncthreads();
#pragma unroll
            for (int n = 0; n < 4; ++n) {
                const int cl = wc * 64 + n * 16 + r16;
                const int c  = col0 + cl;
                const float nmc = (c < IMGn) ? 0.f : (float)nm[c];
#pragma unroll
                for (int m = 0; m < 4; ++m)
#pragma unroll
                    for (int i = 0; i < 4; ++i) {
                        const int rl = wr * 64 + m * 16 + s * 4 + i;
                        const int r  = row0 + rl;
                        float mask;
                        if (r < IMGn)      mask = nmc;
                        else if (c < IMGn) mask = (float)nm[r];
                        else               mask = 1.f;
                        lt[cl * 136 + rl] = f2b(acc[m][n][i] * mask);
                    }
            }
            __syncthreads();
            const bf16x8* srcv = (const bf16x8*)(lt + (size_t)row * 136 + h * 64);
            bf16x8* dstv = (bf16x8*)(out + (size_t)(col0 + row) * Nn + row0 + h * 64);
#pragma unroll
            for (int q = 0; q < 8; ++q) dstv[q] = srcv[q];
        }
    } else {                                               // ---- TRANS1 ----
        const int idx = xcd * 64 + (gid - 80);             // 0..511
        const int tx = idx & 1, ty = idx >> 1;
        gemm_loop(A0 + (size_t)ty * 128 * Dn, w0b + (size_t)tx * 128 * Dn,
                  Dn, Dn, 8, smem, tid, wr, wc, r16, s, acc);
        unsigned short* lt = (unsigned short*)smem;
#pragma unroll
        for (int n = 0; n < 4; ++n)
#pragma unroll
            for (int m = 0; m < 4; ++m)
#pragma unroll
                for (int i = 0; i < 4; ++i) {
                    const int ct = wc * 64 + n * 16 + r16;
                    const int rt = wr * 64 + m * 16 + s * 4 + i;
                    lt[ct * 136 + rt] = f2b(acc[m][n][i]);
                }
        __syncthreads();
        const size_t bb = ty >> 2;
        const int rl0 = (ty & 3) * 128, col0 = tx * 128;
        unsigned short* out = Ut + bb * ((size_t)Dn * Nn);
        const int ct = tid >> 1, h = tid & 1;
        const bf16x8* srcv = (const bf16x8*)(lt + (size_t)ct * 136 + h * 64);
        bf16x8* dstv = (bf16x8*)(out + (size_t)(col0 + ct) * Nn + rl0 + h * 64);
#pragma unroll
        for (int q = 0; q < 8; ++q) dstv[q] = srcv[q];
    }
}

// ---- H = relu(adj @ Ut^T + bias) (512 blocks) ---------------------------------
__global__ __launch_bounds__(256, 4) void k_biash(const unsigned short* __restrict__ adj,
                                                  const unsigned short* __restrict__ Ut,
                                                  const float* __restrict__ bias,
                                                  unsigned short* __restrict__ H) {
    __shared__ char smem[34816];
    const int tid = threadIdx.x, lane = tid & 63, wave = tid >> 6;
    const int wr = wave >> 1, wc = wave & 1;
    const int r16 = lane & 15, s = lane >> 4;
    const int id = blockIdx.x, xcd = id & 7, gid = id >> 3;   // gid 0..63
    const int b = xcd * 8 + (gid >> 3);
    const int tile = gid & 7, tx = tile & 1, ty = tile >> 1;
    f32x4 acc[4][4];
    gemm_loop(adj + (size_t)b * Nn * Nn + (size_t)ty * 128 * Nn,
              Ut  + (size_t)b * Dn * Nn + (size_t)tx * 128 * Nn,
              Nn, Nn, 16, smem, tid, wr, wc, r16, s, acc);
    const int row0 = ty * 128, col0 = tx * 128;
    unsigned short* lt = (unsigned short*)smem;
#pragma unroll
    for (int n = 0; n < 4; ++n) {
        const int cl = wc * 64 + n * 16 + r16;
        const float bvv = bias[col0 + cl];
#pragma unroll
        for (int m = 0; m < 4; ++m)
#pragma unroll
            for (int i = 0; i < 4; ++i) {
                const int rl = wr * 64 + m * 16 + s * 4 + i;
                lt[rl * 136 + cl] = f2b(fmaxf(acc[m][n][i] + bvv, 0.f));
            }
    }
    __syncthreads();
    unsigned short* out = H + (size_t)b * Nn * Dn;
    const int row = tid >> 1, h = tid & 1;
    const bf16x8* srcv = (const bf16x8*)(lt + (size_t)row * 136 + h * 64);
    bf16x8* dstv = (bf16x8*)(out + (size_t)(row0 + row) * Dn + col0 + h * 64);
#pragma unroll
    for (int q = 0; q < 8; ++q) dstv[q] = srcv[q];
}

// ---- Ut = (Hin @ W^T)^T (512 blocks) ------------------------------------------
__global__ __launch_bounds__(256, 4) void k_trans(const unsigned short* __restrict__ Hin,
                                                  const unsigned short* __restrict__ Wb,
                                                  unsigned short* __restrict__ Ut) {
    __shared__ char smem[34816];
    const int tid = threadIdx.x, lane = tid & 63, wave = tid >> 6;
    const int wr = wave >> 1, wc = wave & 1;
    const int r16 = lane & 15, s = lane >> 4;
    const int id = blockIdx.x, xcd = id & 7;
    const int idx = xcd * 64 + (id >> 3);
    const int tx = idx & 1, ty = idx >> 1;
    f32x4 acc[4][4];
    gemm_loop(Hin + (size_t)ty * 128 * Dn, Wb + (size_t)tx * 128 * Dn,
              Dn, Dn, 8, smem, tid, wr, wc, r16, s, acc);
    unsigned short* lt = (unsigned short*)smem;
#pragma unroll
    for (int n = 0; n < 4; ++n)
#pragma unroll
        for (int m = 0; m < 4; ++m)
#pragma unroll
            for (int i = 0; i < 4; ++i) {
                const int ct = wc * 64 + n * 16 + r16;
                const int rt = wr * 64 + m * 16 + s * 4 + i;
                lt[ct * 136 + rt] = f2b(acc[m][n][i]);
            }
    __syncthreads();
    const size_t bb = ty >> 2;
    const int rl0 = (ty & 3) * 128, col0 = tx * 128;
    unsigned short* out = Ut + bb * ((size_t)Dn * Nn);
    const int ct = tid >> 1, h = tid & 1;
    const bf16x8* srcv = (const bf16x8*)(lt + (size_t)ct * 136 + h * 64);
    bf16x8* dstv = (bf16x8*)(out + (size_t)(col0 + ct) * Nn + rl0 + h * 64);
#pragma unroll
    for (int q = 0; q < 8; ++q) dstv[q] = srcv[q];
}

// ---- out = relu(H2 @ wf^T + bf), fp32 (512 blocks) ----------------------------
__global__ __launch_bounds__(256, 4) void k_final(const unsigned short* __restrict__ H2,
                                                  const unsigned short* __restrict__ wfb,
                                                  const float* __restrict__ bias,
                                                  float* __restrict__ out) {
    __shared__ char smem[34816];
    const int tid = threadIdx.x, lane = tid & 63, wave = tid >> 6;
    const int wr = wave >> 1, wc = wave & 1;
    const int r16 = lane & 15, s = lane >> 4;
    const int id = blockIdx.x, xcd = id & 7;
    const int idx = xcd * 64 + (id >> 3);
    const int tx = idx & 1, ty = idx >> 1;
    f32x4 acc[4][4];
    gemm_loop(H2 + (size_t)ty * 128 * Dn, wfb + (size_t)tx * 128 * Dn,
              Dn, Dn, 8, smem, tid, wr, wc, r16, s, acc);
    const int row0 = ty * 128, col0 = tx * 128;
    float* lt32 = (float*)smem;                            // [128][68]
    const int row = tid >> 1, h = tid & 1;
#pragma unroll
    for (int p = 0; p < 2; ++p) {
        if (p) __syncthreads();
        if (wc == p) {
#pragma unroll
            for (int n = 0; n < 4; ++n) {
                const int cll = n * 16 + r16;
                const float bvv = bias[col0 + p * 64 + cll];
#pragma unroll
                for (int m = 0; m < 4; ++m)
#pragma unroll
                    for (int i = 0; i < 4; ++i) {
                        const int rl = wr * 64 + m * 16 + s * 4 + i;
                        lt32[rl * 68 + cll] = fmaxf(acc[m][n][i] + bvv, 0.f);
                    }
            }
        }
        __syncthreads();
        const float4* srcv = (const float4*)(lt32 + (size_t)row * 68 + h * 32);
        float4* dstv = (float4*)(out + (size_t)(row0 + row) * Dn + col0 + p * 64 + h * 32);
#pragma unroll
        for (int q = 0; q < 8; ++q) dstv[q] = srcv[q];
    }
}

extern "C" void kernel_launch(void* const* d_in, const int* in_sizes, int n_in,
                              void* d_out, int out_size, void* d_ws, size_t ws_size,
                              hipStream_t stream) {
    const float* input_1 = (const float*)d_in[0];
    const float* input_2 = (const float*)d_in[1];
    const int*   noun    = (const int*)d_in[3];
    const float* w0 = (const float*)d_in[4];
    const float* b0 = (const float*)d_in[5];
    const float* w1 = (const float*)d_in[6];
    const float* b1 = (const float*)d_in[7];
    const float* wf = (const float*)d_in[8];
    const float* bf = (const float*)d_in[9];

    unsigned short* ws  = (unsigned short*)d_ws;
    unsigned short* T   = ws;                    // 64*512*256
    unsigned short* A0  = ws +  8388608;         // input_1 bf16
    unsigned short* adj = ws + 16777216;         // 64*512*512
    unsigned short* Ut  = ws + 33554432;         // 64*256*512
    unsigned short* H1  = ws + 41943040;
    unsigned short* H2  = ws + 50331648;
    unsigned short* w0b = ws + 58720256;
    unsigned short* w1b = w0b + 65536;
    unsigned short* wfb = w1b + 65536;

    dim3 blk(256);
    k_prep<<<10432, blk, 0, stream>>>(input_1, input_2, w0, w1, wf, A0, T, w0b, w1b, wfb);
    // GRAM upper-tri (640, mirror-stored) + TRANS1 (512) merged = 1152 blocks
    k_gt<<<1152, blk, 0, stream>>>(T, A0, w0b, noun, adj, Ut);
    // H1 = relu(adj @ Ut0^T + b0)
    k_biash<<<512, blk, 0, stream>>>(adj, Ut, b0, H1);
    // Ut1 = (H1 @ w1^T)^T
    k_trans<<<512, blk, 0, stream>>>(H1, w1b, Ut);
    // H2 = relu(adj @ Ut1^T + b1)
    k_biash<<<512, blk, 0, stream>>>(adj, Ut, b1, H2);
    // out = relu(H2 @ wf^T + bf)
    k_final<<<512, blk, 0, stream>>>(H2, wfb, bf, (float*)d_out);
}